// Round 8
// baseline (472.377 us; speedup 1.0000x reference)
//
#include <hip/hip_runtime.h>
#include <math.h>

// Problem constants (fixed by reference): B=1024, NMAX=128, D=256, NUM=4
#define BB   1024
#define DD   256
#define LOGD 5.5451774444795624753f   // log(256)

typedef __attribute__((ext_vector_type(8))) short short8;   // 8 bf16 = 4 VGPRs
typedef __attribute__((ext_vector_type(4))) float f32x4;    // MFMA acc

__device__ __forceinline__ float wave_sum(float v){
  #pragma unroll
  for (int off=32; off>0; off>>=1) v += __shfl_xor(v, off, 64);
  return v;
}
__device__ __forceinline__ float wave_max(float v){
  #pragma unroll
  for (int off=32; off>0; off>>=1) v = fmaxf(v, __shfl_xor(v, off, 64));
  return v;
}
__device__ __forceinline__ float fast_tanh(float x){
  return 1.0f - 2.0f/(__expf(2.0f*x)+1.0f);
}
__device__ __forceinline__ unsigned short f2bf(float f){
  unsigned int u = __float_as_uint(f);
  unsigned int r = u + 0x7FFFu + ((u >> 16) & 1u);   // RNE
  return (unsigned short)(r >> 16);
}

// ---- K_pre: fused prologue (castW + bounds + params), one launch ----
__global__ void k_pre(const float* __restrict__ W1, unsigned short* __restrict__ w1b,
                      const int* __restrict__ batch, int T, int* __restrict__ starts,
                      const float* __restrict__ rho, const float* __restrict__ a1,
                      const float* __restrict__ a2, const float* __restrict__ a3,
                      float* __restrict__ P)
{
  const int blk = blockIdx.x, tid = threadIdx.x;
  if (blk < 64){
    const int t = blk*256 + tid;
    #pragma unroll
    for (int i=0;i<2;i++){
      const int idx = (t*2 + i)*4;
      const float4 v = *(const float4*)(W1 + idx);
      *(ushort4*)(w1b + idx) = make_ushort4(f2bf(v.x), f2bf(v.y), f2bf(v.z), f2bf(v.w));
    }
  } else if (blk < 69){
    const int b = (blk-64)*256 + tid;
    if (b <= BB){
      int lo = 0, hi = T;
      while (lo < hi){ int mid = (lo+hi)>>1; if (batch[mid] < b) lo = mid+1; else hi = mid; }
      starts[b] = lo;
    }
  } else if (tid == 0){
    // P: [0..3]=r [4..7]=1/(b1+r) [8..11]=1/(b2+r) [12..15]=log_mu@k [16..19]=b3 [20..23]=1/(b3+r)
    float lm = -LOGD, z1 = 0.f;
    for (int k=0;k<4;k++){
      float r  = log1pf(expf(rho[k]));
      float b1 = log1pf(expf(a1[k]));
      float b2 = log1pf(expf(a2[k]));
      float b3 = log1pf(expf(a3[k]));
      P[k]    = r;
      P[4+k]  = 1.f/(b1+r);
      P[8+k]  = 1.f/(b2+r);
      P[12+k] = lm;
      P[16+k] = b3;
      P[20+k] = 1.f/(b3+r);
      float lmn = (b3*(-LOGD) - z1 + r*lm)/(b3+r);
      z1 += r*(expf(lmn)-expf(lm));
      lm = lmn;
    }
  }
}

// ---- K2: fused MLP, single pass over x ----
// One block = 128 rows x ALL 512 hidden. X tile (K=256, bf16) resident in LDS,
// staged+converted ONCE; W streamed per hidden-quarter from L2 (w1b 256 KB is
// L2-resident). acc regs reused across quarters (per-quarter epilogue into
// lred). logits written with a plain store - no global atomics, no memset.
// x HBM traffic: 1x (was 4x). LDS 135.7 KB -> 1 block/CU, 8 waves.
#define LPX 264   // row stride in shorts (528 B): frag b128 reads 2-way = free
__global__ __launch_bounds__(512, 2) void k_mlp(
    const float* __restrict__ x, const unsigned short* __restrict__ w1b,
    const float* __restrict__ W2, float* __restrict__ logits, int T)
{
  __shared__ unsigned short Xs[128*LPX];   // 67584 B
  __shared__ unsigned short Ws[128*LPX];   // 67584 B
  __shared__ float lred[128];
  const int bx = blockIdx.x;   // row tile
  const int tid = threadIdx.x;
  if (tid < 128) lred[tid] = 0.f;

  const int srow = tid >> 2, sseg = tid & 3;   // staging: row, 64-elem chunk
  // stage X once (fp32 -> bf16)
  {
    const int grow = bx*128 + srow;
    #pragma unroll
    for (int i=0;i<16;i++){
      float4 v = make_float4(0.f,0.f,0.f,0.f);
      if (grow < T) v = *(const float4*)(x + (size_t)grow*DD + sseg*64 + i*4);
      *(ushort4*)&Xs[srow*LPX + sseg*64 + i*4] =
          make_ushort4(f2bf(v.x), f2bf(v.y), f2bf(v.z), f2bf(v.w));
    }
  }

  const int l = tid & 63;
  const int w = tid >> 6;             // wave 0..7
  const int wm = w >> 2;              // M half (0..1)
  const int wn = w & 3;               // N quarter within the 128-wide W tile
  const int lr = l & 15, quad = l >> 4;

  for (int hq=0; hq<4; hq++){
    __syncthreads();   // previous quarter's Ws readers done (also X/lred ready at hq=0)
    // stage W quarter (128 hidden x 256 k, already bf16): 8 short8 per thread
    #pragma unroll
    for (int i=0;i<8;i++){
      *(short8*)&Ws[srow*LPX + sseg*64 + i*8] =
          *(const short8*)(w1b + (size_t)(hq*128 + srow)*DD + sseg*64 + i*8);
    }
    __syncthreads();   // Ws ready

    f32x4 acc[4][2];
    #pragma unroll
    for (int mi=0;mi<4;mi++)
      #pragma unroll
      for (int ni=0;ni<2;ni++) acc[mi][ni] = (f32x4){0.f,0.f,0.f,0.f};
    #pragma unroll
    for (int ks=0; ks<8; ks++){
      short8 afr[4], bfr[2];
      #pragma unroll
      for (int mi=0;mi<4;mi++)
        afr[mi] = *(const short8*)&Xs[(wm*64 + mi*16 + lr)*LPX + ks*32 + quad*8];
      #pragma unroll
      for (int ni=0;ni<2;ni++)
        bfr[ni] = *(const short8*)&Ws[(wn*32 + ni*16 + lr)*LPX + ks*32 + quad*8];
      #pragma unroll
      for (int mi=0;mi<4;mi++)
        #pragma unroll
        for (int ni=0;ni<2;ni++)
          acc[mi][ni] = __builtin_amdgcn_mfma_f32_16x16x32_bf16(afr[mi], bfr[ni], acc[mi][ni], 0, 0, 0);
    }
    // epilogue for this quarter: tanh + dot W2 + 16-lane reduce
    float w2v[2];
    #pragma unroll
    for (int ni=0;ni<2;ni++) w2v[ni] = W2[hq*128 + wn*32 + ni*16 + lr];
    #pragma unroll
    for (int mi=0;mi<4;mi++){
      float p[4];
      #pragma unroll
      for (int v=0; v<4; v++){
        p[v] = fast_tanh(acc[mi][0][v])*w2v[0] + fast_tanh(acc[mi][1][v])*w2v[1];
        #pragma unroll
        for (int off=1; off<16; off<<=1) p[v] += __shfl_xor(p[v], off, 64);
      }
      if (lr == 0){
        #pragma unroll
        for (int v=0; v<4; v++)
          atomicAdd(&lred[wm*64 + mi*16 + quad*4 + v], p[v]);
      }
    }
  }
  __syncthreads();
  if (tid < 128){
    const int grow = bx*128 + tid;
    if (grow < T) logits[grow] = lred[tid];   // plain store: all 512 hidden in-block
  }
}

// ---- K4: BADMM solver, one block per batch, single sweep per iteration ----
// r7 structure (4 fused A-sweeps, fp32 A, register eta/z2, fused softmax, no
// max-subtraction) with the column reduction switched to LDS atomicAdd into a
// 3-buffer rotation: 5 barriers total (was 8) and no serial 16-way reduce
// phase. LDS 134 KB -> 1 block/CU (accepted; VGPR-cliff attempts r3/r5/r6 all
// failed). Do NOT force high min-waves/EU (r3: spills to scratch).
__global__ __launch_bounds__(1024, 4) void k_solver(
    const float* __restrict__ x, const float* __restrict__ logits,
    const int* __restrict__ starts, const float* __restrict__ P,
    float* __restrict__ out)
{
  __shared__ float A[128*DD];      // 128 KB: log_s / log_t state
  __shared__ float cols[3][DD];    // 3 KB rotating column-sum buffers
  const int b = blockIdx.x;
  const int start = starts[b];
  const int len = starts[b+1] - start;
  const int tid = threadIdx.x;
  const int w = tid >> 6, l = tid & 63;
  const int n0 = w*8;
  int nv = len - n0; nv = nv < 0 ? 0 : (nv > 8 ? 8 : nv);

  const float r0=P[0], r1=P[1], r2=P[2], r3=P[3];
  const float i10=P[4], i11=P[5], i12=P[6];
  const float i20=P[8], i21=P[9], i22=P[10], i23=P[11];
  const float mu0=P[12], mu1=P[13], mu2=P[14];
  const float b30=P[16], b31=P[17], b32=P[18];
  const float e30=P[20], e31=P[21], e32=P[22];

  // ---- fused segment softmax (per-wave redundant) ----
  const float* lg = logits + start;
  float v0 = (l      < len) ? lg[l]    : -3.0e38f;
  float v1 = (l+64   < len) ? lg[l+64] : -3.0e38f;
  float sm = wave_max(fmaxf(v0,v1));
  float se0 = (l    < len) ? __expf(v0-sm) : 0.f;
  float se1 = (l+64 < len) ? __expf(v1-sm) : 0.f;
  float ssum = wave_sum(se0+se1);
  const float sinv = 1.f/(ssum + 1e-16f);
  const float esel = (n0 < 64) ? se0 : se1;   // wave-uniform selector

  float lq[8], eta[8], z2r[8];
  float z[8][4];
  #pragma unroll
  for (int r=0;r<8;r++){
    const float ev = __shfl(esel, (n0+r)&63, 64);
    lq[r]  = __logf(ev*sinv + 1e-8f);
    eta[r] = lq[r];
    z2r[r] = 0.f;
    #pragma unroll
    for (int j=0;j<4;j++) z[r][j]=0.f;
  }
  if (tid < DD){ cols[0][tid] = 0.f; cols[1][tid] = 0.f; }
  __syncthreads();   // cols[0]/[1] zeroed before sweep-0 atomics

  // ---- sweep 0: T-update(k=0) from registers + colsum -> cols[0] ----
  {
    float sp[4] = {0.f,0.f,0.f,0.f};
    #pragma unroll
    for (int r=0;r<8;r++){
      if (r < nv){
        const float* xp = x + (size_t)(start+n0+r)*DD + l;
        const int base = (n0+r)*DD + l;
        const float a0 = lq[r] - LOGD;        // initial log_s (uniform per row)
        float xv[4], y[4];
        #pragma unroll
        for (int j=0;j<4;j++) xv[j] = xp[64*j];
        #pragma unroll
        for (int j=0;j<4;j++) y[j] = (xv[j] + r0*a0) * i20;
        float se = 0.f;
        #pragma unroll
        for (int j=0;j<4;j++) se += __expf(y[j]);
        se = wave_sum(se);
        const float off = eta[r] - __logf(se);
        #pragma unroll
        for (int j=0;j<4;j++){
          const float lt = off + y[j];
          A[base+64*j] = lt;
          sp[j] += __expf((r0*lt) * i10);     // z=0
        }
        const float en = (b30*lq[r] - z2r[r] + r0*eta[r]) * e30;
        z2r[r] += r0*(__expf(en) - __expf(eta[r]));
        eta[r] = en;
      }
    }
    if (nv > 0){
      #pragma unroll
      for (int j=0;j<4;j++) atomicAdd(&cols[0][l+64*j], sp[j]);
    }
  }
  __syncthreads();   // cols[0] final

  // ---- sweeps 1..2: S(k-1) + z-update + T(k) + colsum(k) ----
  // sweep m: lsc from cols[(m-1)%3], accumulate cols[m%3], zero cols[(m+1)%3]
  #pragma unroll
  for (int k=1;k<3;k++){
    const float rkm = (k==1)? r0 : r1;
    const float ib1m= (k==1)? i10 : i11;
    const float mum = (k==1)? mu0 : mu1;
    const float rk  = (k==1)? r1 : r2;
    const float ib1k= (k==1)? i11 : i12;
    const float ib2k= (k==1)? i21 : i22;
    const float b3k = (k==1)? b31 : b32;
    const float e3k = (k==1)? e31 : e32;
    const int pm = (k-1)%3, pc = k%3, pz = (k+1)%3;
    float lsc[4];
    #pragma unroll
    for (int j=0;j<4;j++) lsc[j] = __logf(cols[pm][l+64*j]);
    if (tid < DD) cols[pz][tid] = 0.f;   // zero next sweep's buffer
    float sp[4] = {0.f,0.f,0.f,0.f};
    #pragma unroll
    for (int r=0;r<8;r++){
      if (r < nv){
        const float* xp = x + (size_t)(start+n0+r)*DD + l;
        const int base = (n0+r)*DD + l;
        float xv[4];
        #pragma unroll
        for (int j=0;j<4;j++) xv[j] = xp[64*j];
        float y[4], lsn[4];
        #pragma unroll
        for (int j=0;j<4;j++){
          const float lt  = A[base+64*j];
          const float ys  = (z[r][j] + rkm*lt) * ib1m;
          lsn[j] = mum + ys - lsc[j];
          z[r][j] += rkm*(__expf(lt) - __expf(lsn[j]));
          y[j] = (xv[j] - z[r][j] + rk*lsn[j]) * ib2k;
        }
        float se = 0.f;
        #pragma unroll
        for (int j=0;j<4;j++) se += __expf(y[j]);
        se = wave_sum(se);
        const float off = eta[r] - __logf(se);
        #pragma unroll
        for (int j=0;j<4;j++){
          const float lt = off + y[j];
          A[base+64*j] = lt;
          sp[j] += __expf((z[r][j] + rk*lt) * ib1k);
        }
        const float en = (b3k*lq[r] - z2r[r] + rk*eta[r]) * e3k;
        z2r[r] += rk*(__expf(en) - __expf(eta[r]));
        eta[r] = en;
      }
    }
    if (nv > 0){
      #pragma unroll
      for (int j=0;j<4;j++) atomicAdd(&cols[pc][l+64*j], sp[j]);
    }
    __syncthreads();   // cols[pc] final (also covers the pz zeroing)
  }

  // ---- sweep 3: S(2) + z-update + T(3) + output (into cols[0], zeroed @k=2) ----
  {
    float lsc[4];
    #pragma unroll
    for (int j=0;j<4;j++) lsc[j] = __logf(cols[2][l+64*j]);
    float op[4] = {0.f,0.f,0.f,0.f};
    #pragma unroll
    for (int r=0;r<8;r++){
      if (r < nv){
        const float* xp = x + (size_t)(start+n0+r)*DD + l;
        const int base = (n0+r)*DD + l;
        float xv[4];
        #pragma unroll
        for (int j=0;j<4;j++) xv[j] = xp[64*j];
        float y[4];
        #pragma unroll
        for (int j=0;j<4;j++){
          const float lt  = A[base+64*j];
          const float ys  = (z[r][j] + r2*lt) * i12;
          const float lsn = mu2 + ys - lsc[j];
          z[r][j] += r2*(__expf(lt) - __expf(lsn));
          y[j] = (xv[j] - z[r][j] + r3*lsn) * i23;
        }
        float ey[4], se = 0.f;
        #pragma unroll
        for (int j=0;j<4;j++){ ey[j] = __expf(y[j]); se += ey[j]; }
        se = wave_sum(se);
        const float rs = __expf(eta[r]) / se;   // t = ey * exp(eta3)/se
        #pragma unroll
        for (int j=0;j<4;j++) op[j] += xv[j]*ey[j]*rs;
      }
    }
    if (nv > 0){
      #pragma unroll
      for (int j=0;j<4;j++) atomicAdd(&cols[0][l+64*j], op[j]);
    }
    __syncthreads();
    if (tid < DD) out[(size_t)b*DD + tid] = 256.0f * cols[0][tid];
  }
}

extern "C" void kernel_launch(void* const* d_in, const int* in_sizes, int n_in,
                              void* d_out, int out_size, void* d_ws, size_t ws_size,
                              hipStream_t stream) {
  const float* x    = (const float*)d_in[0];
  const int*   batch= (const int*)d_in[1];
  const float* W1   = (const float*)d_in[2];
  const float* W2   = (const float*)d_in[3];
  const float* rho  = (const float*)d_in[4];
  const float* a1   = (const float*)d_in[5];
  const float* a2   = (const float*)d_in[6];
  const float* a3   = (const float*)d_in[7];
  float* out = (float*)d_out;
  const int T = in_sizes[1];   // total ragged rows

  float* logits = (float*)d_ws;              // T floats
  int*   starts = (int*)(logits + T);        // B+1 ints (padded to 1028)
  float* P      = (float*)(starts + 1028);   // 24 floats (padded to 32)
  unsigned short* w1b = (unsigned short*)(P + 32);  // 512*256 bf16

  k_pre<<<70, 256, 0, stream>>>(W1, w1b, batch, T, starts, rho, a1, a2, a3, P);
  k_mlp<<<dim3((T+127)/128), 512, 0, stream>>>(x, w1b, W2, logits, T);
  k_solver<<<BB, 1024, 0, stream>>>(x, logits, starts, P, out);
}

// Round 9
// 358.696 us; speedup vs baseline: 1.3169x; 1.3169x over previous
//
#include <hip/hip_runtime.h>
#include <math.h>

// Problem constants (fixed by reference): B=1024, NMAX=128, D=256, NUM=4
#define BB   1024
#define DD   256
#define LOGD 5.5451774444795624753f   // log(256)

typedef __attribute__((ext_vector_type(8))) short short8;   // 8 bf16 = 4 VGPRs
typedef __attribute__((ext_vector_type(4))) float f32x4;    // MFMA acc

__device__ __forceinline__ float wave_sum(float v){
  #pragma unroll
  for (int off=32; off>0; off>>=1) v += __shfl_xor(v, off, 64);
  return v;
}
__device__ __forceinline__ float wave_max(float v){
  #pragma unroll
  for (int off=32; off>0; off>>=1) v = fmaxf(v, __shfl_xor(v, off, 64));
  return v;
}
__device__ __forceinline__ float fast_tanh(float x){
  return 1.0f - 2.0f/(__expf(2.0f*x)+1.0f);
}
__device__ __forceinline__ unsigned short f2bf(float f){
  unsigned int u = __float_as_uint(f);
  unsigned int r = u + 0x7FFFu + ((u >> 16) & 1u);   // RNE
  return (unsigned short)(r >> 16);
}

// ---- K_pre: fused prologue (castW + bounds + params), one launch ----
__global__ void k_pre(const float* __restrict__ W1, unsigned short* __restrict__ w1b,
                      const int* __restrict__ batch, int T, int* __restrict__ starts,
                      const float* __restrict__ rho, const float* __restrict__ a1,
                      const float* __restrict__ a2, const float* __restrict__ a3,
                      float* __restrict__ P)
{
  const int blk = blockIdx.x, tid = threadIdx.x;
  if (blk < 64){
    const int t = blk*256 + tid;
    #pragma unroll
    for (int i=0;i<2;i++){
      const int idx = (t*2 + i)*4;
      const float4 v = *(const float4*)(W1 + idx);
      *(ushort4*)(w1b + idx) = make_ushort4(f2bf(v.x), f2bf(v.y), f2bf(v.z), f2bf(v.w));
    }
  } else if (blk < 69){
    const int b = (blk-64)*256 + tid;
    if (b <= BB){
      int lo = 0, hi = T;
      while (lo < hi){ int mid = (lo+hi)>>1; if (batch[mid] < b) lo = mid+1; else hi = mid; }
      starts[b] = lo;
    }
  } else if (tid == 0){
    // P: [0..3]=r [4..7]=1/(b1+r) [8..11]=1/(b2+r) [12..15]=log_mu@k [16..19]=b3 [20..23]=1/(b3+r)
    float lm = -LOGD, z1 = 0.f;
    for (int k=0;k<4;k++){
      float r  = log1pf(expf(rho[k]));
      float b1 = log1pf(expf(a1[k]));
      float b2 = log1pf(expf(a2[k]));
      float b3 = log1pf(expf(a3[k]));
      P[k]    = r;
      P[4+k]  = 1.f/(b1+r);
      P[8+k]  = 1.f/(b2+r);
      P[12+k] = lm;
      P[16+k] = b3;
      P[20+k] = 1.f/(b3+r);
      float lmn = (b3*(-LOGD) - z1 + r*lm)/(b3+r);
      z1 += r*(expf(lmn)-expf(lm));
      lm = lmn;
    }
  }
}

// ---- K2: fused MLP via bf16 MFMA (r7/r6 structure; tile 128x128, BK=64) ----
// ONE change vs r7: __launch_bounds__(512, 4) caps VGPR at 128 (needs ~90:
// 32 acc + 24 frags + addressing) and guarantees 2 blocks/CU (LDS 37KB x2 =
// 74 <= 160). r1-r8's (512,2) left the allocator free up to 256 VGPR, which
// could silently pin k_mlp at 1 block/CU - the suspected reason every k_mlp
// variant landed at ~160-200 us vs ~50 us of actual work.
#define LPW 72
__global__ __launch_bounds__(512, 4) void k_mlp(
    const float* __restrict__ x, const unsigned short* __restrict__ w1b,
    const float* __restrict__ W2, float* __restrict__ logits, int T)
{
  __shared__ unsigned short Xs[128*LPW];   // 18432 B
  __shared__ unsigned short Ws[128*LPW];   // 18432 B
  __shared__ float lred[128];
  const int by = blockIdx.x;   // hidden quarter 0..3
  const int bx = blockIdx.y;   // row tile
  const int tid = threadIdx.x;
  if (tid < 128) lred[tid] = 0.f;

  const int l = tid & 63;
  const int w = tid >> 6;             // wave 0..7
  const int wm = w >> 2;              // M half (0..1)
  const int wn = w & 3;               // N quarter (0..3)
  const int lr = l & 15, quad = l >> 4;
  const int srow = tid >> 2;          // x-staging row 0..127
  const int sseg = tid & 3;           // 16-float segment of BK=64
  const int wrow = tid >> 3;          // w-staging row 0..63 (x2 halves)
  const int wseg = tid & 7;           // 8-short chunk

  f32x4 acc[4][2];
  #pragma unroll
  for (int mi=0;mi<4;mi++)
    #pragma unroll
    for (int ni=0;ni<2;ni++) acc[mi][ni] = (f32x4){0.f,0.f,0.f,0.f};

  for (int kt=0; kt<4; kt++){
    const int k0 = kt*64;
    {
      const int grow = bx*128 + srow;
      #pragma unroll
      for (int i=0;i<4;i++){
        float4 v = make_float4(0.f,0.f,0.f,0.f);
        if (grow < T) v = *(const float4*)(x + (size_t)grow*DD + k0 + sseg*16 + i*4);
        *(ushort4*)&Xs[srow*LPW + sseg*16 + i*4] =
            make_ushort4(f2bf(v.x), f2bf(v.y), f2bf(v.z), f2bf(v.w));
      }
    }
    #pragma unroll
    for (int h=0; h<2; h++){
      const int r = h*64 + wrow;
      *(short8*)&Ws[r*LPW + wseg*8] =
          *(const short8*)(w1b + (size_t)(by*128 + r)*DD + k0 + wseg*8);
    }
    __syncthreads();
    #pragma unroll
    for (int ks=0; ks<2; ks++){
      short8 afr[4], bfr[2];
      #pragma unroll
      for (int mi=0;mi<4;mi++)
        afr[mi] = *(const short8*)&Xs[(wm*64 + mi*16 + lr)*LPW + ks*32 + quad*8];
      #pragma unroll
      for (int ni=0;ni<2;ni++)
        bfr[ni] = *(const short8*)&Ws[(wn*32 + ni*16 + lr)*LPW + ks*32 + quad*8];
      #pragma unroll
      for (int mi=0;mi<4;mi++)
        #pragma unroll
        for (int ni=0;ni<2;ni++)
          acc[mi][ni] = __builtin_amdgcn_mfma_f32_16x16x32_bf16(afr[mi], bfr[ni], acc[mi][ni], 0, 0, 0);
    }
    __syncthreads();
  }

  float w2v[2];
  #pragma unroll
  for (int ni=0;ni<2;ni++) w2v[ni] = W2[by*128 + wn*32 + ni*16 + lr];
  #pragma unroll
  for (int mi=0;mi<4;mi++){
    float p[4];
    #pragma unroll
    for (int v=0; v<4; v++){
      p[v] = fast_tanh(acc[mi][0][v])*w2v[0] + fast_tanh(acc[mi][1][v])*w2v[1];
      #pragma unroll
      for (int off=1; off<16; off<<=1) p[v] += __shfl_xor(p[v], off, 64);
    }
    if (lr == 0){
      #pragma unroll
      for (int v=0; v<4; v++)
        atomicAdd(&lred[wm*64 + mi*16 + quad*4 + v], p[v]);
    }
  }
  __syncthreads();
  if (tid < 128){
    const int grow = bx*128 + tid;
    if (grow < T) atomicAdd(logits + grow, lred[tid]);
  }
}

// ---- K4: BADMM solver - EXACT r7 version (136 us measured) ----
// 4 fused A-sweeps, fp32 A, per-wave red[] slices + serial 16-way reduce.
// r8 lesson: LDS float atomicAdd colsum (16-wave contention) costs ~70 us -
// per-wave private partials + tree reduce wins. LDS 145 KB -> 1 block/CU
// (accepted; VGPR-cliff unreachable, r3/r5/r6). No forced min-waves (r3 spills).
__global__ __launch_bounds__(1024, 4) void k_solver(
    const float* __restrict__ x, const float* __restrict__ logits,
    const int* __restrict__ starts, const float* __restrict__ P,
    float* __restrict__ out)
{
  __shared__ float A[128*DD];      // 128 KB: log_s / log_t state
  __shared__ float red[16*DD];     // 16 KB: column partials
  __shared__ float colv[DD];       // 1 KB: column LSE
  const int b = blockIdx.x;
  const int start = starts[b];
  const int len = starts[b+1] - start;
  const int tid = threadIdx.x;
  const int w = tid >> 6, l = tid & 63;
  const int n0 = w*8;
  int nv = len - n0; nv = nv < 0 ? 0 : (nv > 8 ? 8 : nv);

  const float r0=P[0], r1=P[1], r2=P[2], r3=P[3];
  const float i10=P[4], i11=P[5], i12=P[6];
  const float i20=P[8], i21=P[9], i22=P[10], i23=P[11];
  const float mu0=P[12], mu1=P[13], mu2=P[14];
  const float b30=P[16], b31=P[17], b32=P[18];
  const float e30=P[20], e31=P[21], e32=P[22];

  // ---- fused segment softmax (per-wave redundant) ----
  const float* lg = logits + start;
  float v0 = (l      < len) ? lg[l]    : -3.0e38f;
  float v1 = (l+64   < len) ? lg[l+64] : -3.0e38f;
  float sm = wave_max(fmaxf(v0,v1));
  float se0 = (l    < len) ? __expf(v0-sm) : 0.f;
  float se1 = (l+64 < len) ? __expf(v1-sm) : 0.f;
  float ssum = wave_sum(se0+se1);
  const float sinv = 1.f/(ssum + 1e-16f);
  const float esel = (n0 < 64) ? se0 : se1;   // wave-uniform selector

  float lq[8], eta[8], z2r[8];
  float z[8][4];
  #pragma unroll
  for (int r=0;r<8;r++){
    const float ev = __shfl(esel, (n0+r)&63, 64);
    lq[r]  = __logf(ev*sinv + 1e-8f);
    eta[r] = lq[r];
    z2r[r] = 0.f;
    #pragma unroll
    for (int j=0;j<4;j++) z[r][j]=0.f;
  }

  // ---- sweep 0: T-update(k=0) from registers + colsum for S(0) ----
  {
    float sp[4] = {0.f,0.f,0.f,0.f};
    #pragma unroll
    for (int r=0;r<8;r++){
      if (r < nv){
        const float* xp = x + (size_t)(start+n0+r)*DD + l;
        const int base = (n0+r)*DD + l;
        const float a0 = lq[r] - LOGD;        // initial log_s (uniform per row)
        float xv[4], y[4];
        #pragma unroll
        for (int j=0;j<4;j++) xv[j] = xp[64*j];
        #pragma unroll
        for (int j=0;j<4;j++) y[j] = (xv[j] + r0*a0) * i20;
        float se = 0.f;
        #pragma unroll
        for (int j=0;j<4;j++) se += __expf(y[j]);
        se = wave_sum(se);
        const float off = eta[r] - __logf(se);
        #pragma unroll
        for (int j=0;j<4;j++){
          const float lt = off + y[j];
          A[base+64*j] = lt;
          sp[j] += __expf((r0*lt) * i10);     // z=0
        }
        const float en = (b30*lq[r] - z2r[r] + r0*eta[r]) * e30;
        z2r[r] += r0*(__expf(en) - __expf(eta[r]));
        eta[r] = en;
      }
    }
    #pragma unroll
    for (int j=0;j<4;j++) red[w*DD + l + 64*j] = sp[j];
  }
  __syncthreads();
  if (tid < DD){
    float s = 0.f;
    #pragma unroll
    for (int ww=0; ww<16; ww++) s += red[ww*DD + tid];
    colv[tid] = __logf(s);
  }
  __syncthreads();

  // ---- sweeps 1..2: S(k-1) + z-update + T(k) + colsum(k) ----
  #pragma unroll
  for (int k=1;k<3;k++){
    const float rkm = (k==1)? r0 : r1;
    const float ib1m= (k==1)? i10 : i11;
    const float mum = (k==1)? mu0 : mu1;
    const float rk  = (k==1)? r1 : r2;
    const float ib1k= (k==1)? i11 : i12;
    const float ib2k= (k==1)? i21 : i22;
    const float b3k = (k==1)? b31 : b32;
    const float e3k = (k==1)? e31 : e32;
    float lsc[4];
    #pragma unroll
    for (int j=0;j<4;j++) lsc[j] = colv[l+64*j];
    float sp[4] = {0.f,0.f,0.f,0.f};
    #pragma unroll
    for (int r=0;r<8;r++){
      if (r < nv){
        const float* xp = x + (size_t)(start+n0+r)*DD + l;
        const int base = (n0+r)*DD + l;
        float xv[4];
        #pragma unroll
        for (int j=0;j<4;j++) xv[j] = xp[64*j];
        float y[4], lsn[4];
        #pragma unroll
        for (int j=0;j<4;j++){
          const float lt  = A[base+64*j];
          const float ys  = (z[r][j] + rkm*lt) * ib1m;
          lsn[j] = mum + ys - lsc[j];
          z[r][j] += rkm*(__expf(lt) - __expf(lsn[j]));
          y[j] = (xv[j] - z[r][j] + rk*lsn[j]) * ib2k;
        }
        float se = 0.f;
        #pragma unroll
        for (int j=0;j<4;j++) se += __expf(y[j]);
        se = wave_sum(se);
        const float off = eta[r] - __logf(se);
        #pragma unroll
        for (int j=0;j<4;j++){
          const float lt = off + y[j];
          A[base+64*j] = lt;
          sp[j] += __expf((z[r][j] + rk*lt) * ib1k);
        }
        const float en = (b3k*lq[r] - z2r[r] + rk*eta[r]) * e3k;
        z2r[r] += rk*(__expf(en) - __expf(eta[r]));
        eta[r] = en;
      }
    }
    #pragma unroll
    for (int j=0;j<4;j++) red[w*DD + l + 64*j] = sp[j];
    __syncthreads();
    if (tid < DD){
      float s = 0.f;
      #pragma unroll
      for (int ww=0; ww<16; ww++) s += red[ww*DD + tid];
      colv[tid] = __logf(s);
    }
    __syncthreads();
  }

  // ---- sweep 3: S(2) + z-update + T(3) + output ----
  {
    float lsc[4];
    #pragma unroll
    for (int j=0;j<4;j++) lsc[j] = colv[l+64*j];
    float op[4] = {0.f,0.f,0.f,0.f};
    #pragma unroll
    for (int r=0;r<8;r++){
      if (r < nv){
        const float* xp = x + (size_t)(start+n0+r)*DD + l;
        const int base = (n0+r)*DD + l;
        float xv[4];
        #pragma unroll
        for (int j=0;j<4;j++) xv[j] = xp[64*j];
        float y[4];
        #pragma unroll
        for (int j=0;j<4;j++){
          const float lt  = A[base+64*j];
          const float ys  = (z[r][j] + r2*lt) * i12;
          const float lsn = mu2 + ys - lsc[j];
          z[r][j] += r2*(__expf(lt) - __expf(lsn));
          y[j] = (xv[j] - z[r][j] + r3*lsn) * i23;
        }
        float ey[4], se = 0.f;
        #pragma unroll
        for (int j=0;j<4;j++){ ey[j] = __expf(y[j]); se += ey[j]; }
        se = wave_sum(se);
        const float rs = __expf(eta[r]) / se;   // t = ey * exp(eta3)/se
        #pragma unroll
        for (int j=0;j<4;j++) op[j] += xv[j]*ey[j]*rs;
      }
    }
    #pragma unroll
    for (int j=0;j<4;j++) red[w*DD + l + 64*j] = op[j];
    __syncthreads();
    if (tid < DD){
      float s = 0.f;
      #pragma unroll
      for (int ww=0; ww<16; ww++) s += red[ww*DD + tid];
      out[(size_t)b*DD + tid] = 256.0f * s;
    }
  }
}

extern "C" void kernel_launch(void* const* d_in, const int* in_sizes, int n_in,
                              void* d_out, int out_size, void* d_ws, size_t ws_size,
                              hipStream_t stream) {
  const float* x    = (const float*)d_in[0];
  const int*   batch= (const int*)d_in[1];
  const float* W1   = (const float*)d_in[2];
  const float* W2   = (const float*)d_in[3];
  const float* rho  = (const float*)d_in[4];
  const float* a1   = (const float*)d_in[5];
  const float* a2   = (const float*)d_in[6];
  const float* a3   = (const float*)d_in[7];
  float* out = (float*)d_out;
  const int T = in_sizes[1];   // total ragged rows

  float* logits = (float*)d_ws;              // T floats
  int*   starts = (int*)(logits + T);        // B+1 ints (padded to 1028)
  float* P      = (float*)(starts + 1028);   // 24 floats (padded to 32)
  unsigned short* w1b = (unsigned short*)(P + 32);  // 512*256 bf16

  k_pre<<<70, 256, 0, stream>>>(W1, w1b, batch, T, starts, rho, a1, a2, a3, P);
  hipMemsetAsync(logits, 0, (size_t)T*sizeof(float), stream);
  k_mlp<<<dim3(4, (T+127)/128), 512, 0, stream>>>(x, w1b, W2, logits, T);
  k_solver<<<BB, 1024, 0, stream>>>(x, logits, starts, P, out);
}